// Round 10
// baseline (38.684 us; speedup 1.0000x reference)
//
#include <hip/hip_runtime.h>
#include <hip/hip_bf16.h>
#include <math.h>

// Problem constants (from reference): N=8 clouds, P=4096 points, D=3
constexpr int NB  = 8;
constexpr int PP  = 4096;
constexpr int NC  = 2 * NB;       // 16 (dir, cloud) pairs

// Kernel A tiling (R5-proven: XPT=4, strided slices, 2048 blocks)
constexpr int TPB = 256;          // threads per block
constexpr int XPT = 4;            // x points per thread
constexpr int XCH = TPB * XPT;    // 1024 x points per block
constexpr int NXC = PP / XCH;     // 4 x chunks
constexpr int NYC = 32;           // strided y slices (stride = NYC)
constexpr int YCH = PP / NYC;     // 128 y points per slice
constexpr int GRIDA = 2 * NB * NXC * NYC;   // 2048 blocks (2x oversubscribed)

// ---- monotone float<->uint key (uint order == float order); min-safe ----
__device__ inline unsigned int fkey(float f) {
    unsigned int b = __float_as_uint(f);
    return (b & 0x80000000u) ? ~b : (b | 0x80000000u);
}
__device__ inline float fdecode(unsigned int k) {
    unsigned int b = (k & 0x80000000u) ? (k & 0x7FFFFFFFu) : ~k;
    return __uint_as_float(b);
}

// ---------------------------------------------------------------------------
// Kernel A: per (dir, cloud, x-chunk, y-slice): partial min-d2 over the
// STRIDED y-slice {yc + 32*t} for 1024 x points (R5's exact proven compute:
// 15.8us measured via R7 probe). Epilogue: 4 deterministic atomicMin's into
// the 16x4096 uint key table instead of 4 ws stores (saves the 8.4MB ws
// round-trip; min is order-independent -> replay-deterministic).
// ---------------------------------------------------------------------------
__global__ __launch_bounds__(TPB, 4) void nn_partial(
    const float* __restrict__ x, const float* __restrict__ y,
    const int* __restrict__ xlen, const int* __restrict__ ylen,
    unsigned int* __restrict__ tab)
{
    __shared__ float4 sy[YCH];

    const int bid = (int)blockIdx.x;
    const int yc  = bid & (NYC - 1);
    const int xc  = (bid >> 5) & (NXC - 1);
    const int n   = (bid >> 7) & (NB - 1);
    const int dir = bid >> 10;

    const float* __restrict__ xs = dir ? y : x;    // query set
    const float* __restrict__ ys = dir ? x : y;    // search set
    const int yl = (dir ? xlen : ylen)[n];         // valid points in search set
    const int ql = (dir ? ylen : xlen)[n];         // valid points in query set

    // ---- stage strided y-slice into LDS as (-2y0, -2y1, -2y2, |y|^2) ----
    const float* __restrict__ yb = ys + (size_t)n * PP * 3;
    if ((int)threadIdx.x < YCH) {
        const int p   = (int)threadIdx.x;
        const int idx = yc + NYC * p;              // < PP always
        float y0 = yb[idx * 3 + 0];
        float y1 = yb[idx * 3 + 1];
        float y2 = yb[idx * 3 + 2];
        sy[p] = make_float4(-2.f * y0, -2.f * y1, -2.f * y2,
                            fmaf(y0, y0, fmaf(y1, y1, y2 * y2)));
    }

    // ---- load XPT x points, wave-contiguous: xi = wbase + k*64 + lane ----
    const int wave  = (int)threadIdx.x >> 6;
    const int lane  = (int)threadIdx.x & 63;
    const int wbase = xc * XCH + wave * (XPT * 64);   // 256 x points per wave

    float px0[XPT], px1[XPT], px2[XPT], a[XPT], emin[XPT];
    const float* __restrict__ xb = xs + (size_t)n * PP * 3;
#pragma unroll
    for (int k = 0; k < XPT; ++k) {
        const int xi = wbase + k * 64 + lane;
        px0[k] = xb[xi * 3 + 0];
        px1[k] = xb[xi * 3 + 1];
        px2[k] = xb[xi * 3 + 2];
        a[k]   = fmaf(px0[k], px0[k], fmaf(px1[k], px1[k], px2[k] * px2[k]));
        emin[k] = INFINITY;
    }
    __syncthreads();

    // trip count: number of valid points in this strided slice
    int jend = (yl - yc + NYC - 1) >> 5;   // ceil((yl-yc)/32), >= 63 always
    if (jend > YCH) jend = YCH;

    // whole-wave skip when every query row this wave owns is padding
    if (ql > wbase) {
        const int j2 = jend & ~1;
#pragma unroll 2
        for (int j = 0; j < j2; j += 2) {
            const float4 u = sy[j];
            const float4 v = sy[j + 1];
#pragma unroll
            for (int k = 0; k < XPT; ++k) {
                float e1 = fmaf(px0[k], u.x, fmaf(px1[k], u.y, fmaf(px2[k], u.z, u.w)));
                float e2 = fmaf(px0[k], v.x, fmaf(px1[k], v.y, fmaf(px2[k], v.z, v.w)));
                emin[k] = fminf(emin[k], fminf(e1, e2));   // -> v_min3_f32
            }
        }
        if (jend & 1) {
            const float4 u = sy[jend - 1];
#pragma unroll
            for (int k = 0; k < XPT; ++k) {
                float e1 = fmaf(px0[k], u.x, fmaf(px1[k], u.y, fmaf(px2[k], u.z, u.w)));
                emin[k] = fminf(emin[k], e1);
            }
        }
        // ---- deterministic min-merge into the key table ----
        unsigned int* __restrict__ w = tab + (size_t)(dir * NB + n) * PP;
#pragma unroll
        for (int k = 0; k < XPT; ++k) {
            atomicMin(&w[wbase + k * 64 + lane], fkey(a[k] + emin[k]));
        }
    }
}

// ---------------------------------------------------------------------------
// Kernel B (single block): decode the 16x4096 key table, mask padded x,
// per-cloud sum + divide by max(len,1), total / NB -> out[0]. 256 threads,
// 256 loads each (256KB, L2/L3-resident, high MLP). Deterministic.
// ---------------------------------------------------------------------------
__global__ __launch_bounds__(256) void reduce_all(
    const unsigned int* __restrict__ tab,
    const int* __restrict__ xlen, const int* __restrict__ ylen,
    float* __restrict__ out)
{
    const int t    = (int)threadIdx.x;
    const int lane = t & 63;
    const int wv   = t >> 6;

    float acc[NC];
#pragma unroll
    for (int c = 0; c < NC; ++c) acc[c] = 0.f;

#pragma unroll 1
    for (int c = 0; c < NC; ++c) {
        const int dir = c >> 3;
        const int n   = c & (NB - 1);
        const int xl  = (dir ? ylen : xlen)[n];
        const unsigned int* __restrict__ w = tab + (size_t)c * PP;
        unsigned int kv[PP / 256];
#pragma unroll
        for (int r = 0; r < PP / 256; ++r) kv[r] = w[r * 256 + t];
        float s = 0.f;
#pragma unroll
        for (int r = 0; r < PP / 256; ++r) {
            const int i = r * 256 + t;
            s += (i < xl) ? fdecode(kv[r]) : 0.f;
        }
        acc[c] = s;
    }

    __shared__ float ls[NC][4];
#pragma unroll
    for (int c = 0; c < NC; ++c) {
        float s = acc[c];
#pragma unroll
        for (int off = 32; off > 0; off >>= 1) s += __shfl_xor(s, off);
        if (lane == 0) ls[c][wv] = s;
    }
    __syncthreads();
    if (t == 0) {
        float tot = 0.f;
        for (int c = 0; c < NC; ++c) {
            const int dir = c >> 3;
            const int n   = c & (NB - 1);
            const int xl  = (dir ? ylen : xlen)[n];
            float s = ls[c][0] + ls[c][1] + ls[c][2] + ls[c][3];
            int d = xl > 1 ? xl : 1;
            tot += s / (float)d;
        }
        out[0] = tot / (float)NB;
    }
}

// ---------------------------------------------------------------------------
// Fallback (ws too small for even 256KB): strided slices, multi-pass; block
// sum + atomicAdd of the pre-divided contribution. Needs d_out zeroed first.
// ---------------------------------------------------------------------------
__global__ __launch_bounds__(TPB) void chamfer_atomic(
    const float* __restrict__ x, const float* __restrict__ y,
    const int* __restrict__ xlen, const int* __restrict__ ylen,
    float* __restrict__ out)
{
    __shared__ float4 sy[YCH];

    int bid = blockIdx.x;
    const int xc  = bid & (NXC - 1);
    const int n   = (bid >> 2) & (NB - 1);
    const int dir = bid >> 5;

    const float* __restrict__ xs = dir ? y : x;
    const float* __restrict__ ys = dir ? x : y;
    const int yl = (dir ? xlen : ylen)[n];
    const int xl = (dir ? ylen : xlen)[n];

    float px0[XPT], px1[XPT], px2[XPT], a[XPT], emin[XPT];
    const int wave  = (int)threadIdx.x >> 6;
    const int lane  = (int)threadIdx.x & 63;
    const int wbase = xc * XCH + wave * (XPT * 64);
    const float* __restrict__ xb = xs + (size_t)n * PP * 3;
#pragma unroll
    for (int k = 0; k < XPT; ++k) {
        const int xi = wbase + k * 64 + lane;
        px0[k] = xb[xi * 3 + 0];
        px1[k] = xb[xi * 3 + 1];
        px2[k] = xb[xi * 3 + 2];
        a[k]   = fmaf(px0[k], px0[k], fmaf(px1[k], px1[k], px2[k] * px2[k]));
        emin[k] = INFINITY;
    }

    const float* __restrict__ yb = ys + (size_t)n * PP * 3;
    for (int yc = 0; yc < NYC; ++yc) {
        __syncthreads();
        if ((int)threadIdx.x < YCH) {
            const int p   = (int)threadIdx.x;
            const int idx = yc + NYC * p;
            float y0 = yb[idx * 3 + 0];
            float y1 = yb[idx * 3 + 1];
            float y2 = yb[idx * 3 + 2];
            sy[p] = make_float4(-2.f * y0, -2.f * y1, -2.f * y2,
                                fmaf(y0, y0, fmaf(y1, y1, y2 * y2)));
        }
        __syncthreads();
        int jend = (yl - yc + NYC - 1) >> 5;
        if (jend > YCH) jend = YCH;
        for (int j = 0; j < jend; ++j) {
            const float4 u = sy[j];
#pragma unroll
            for (int k = 0; k < XPT; ++k) {
                float e = fmaf(px0[k], u.x, fmaf(px1[k], u.y, fmaf(px2[k], u.z, u.w)));
                emin[k] = fminf(emin[k], e);
            }
        }
    }

    float sum = 0.f;
#pragma unroll
    for (int k = 0; k < XPT; ++k) {
        const int xi = wbase + k * 64 + lane;
        if (xi < xl) sum += a[k] + emin[k];
    }
#pragma unroll
    for (int off = 32; off > 0; off >>= 1) sum += __shfl_xor(sum, off);
    __shared__ float ls[4];
    if (lane == 0) ls[wave] = sum;
    __syncthreads();
    if (threadIdx.x == 0) {
        float tot = ls[0] + ls[1] + ls[2] + ls[3];
        int d = xl > 1 ? xl : 1;
        atomicAdd(out, tot / (float)d / (float)NB);
    }
}

extern "C" void kernel_launch(void* const* d_in, const int* in_sizes, int n_in,
                              void* d_out, int out_size, void* d_ws, size_t ws_size,
                              hipStream_t stream) {
    const float* x  = (const float*)d_in[0];
    const float* y  = (const float*)d_in[1];
    const int* xl   = (const int*)d_in[2];
    const int* yl   = (const int*)d_in[3];
    float* out      = (float*)d_out;

    const size_t tab_bytes = (size_t)NC * PP * sizeof(unsigned int);   // 256 KB

    if (ws_size >= tab_bytes) {
        unsigned int* tab = (unsigned int*)d_ws;
        // init keys to 0xFFFFFFFF (= +max key); graph-capture-safe async memset
        hipMemsetAsync(tab, 0xFF, tab_bytes, stream);
        nn_partial<<<GRIDA, TPB, 0, stream>>>(x, y, xl, yl, tab);
        reduce_all<<<1, 256, 0, stream>>>(tab, xl, yl, out);
    } else {
        hipMemsetAsync(d_out, 0, sizeof(float), stream);
        const int gridF = 2 * NB * NXC;         // 64 blocks
        chamfer_atomic<<<gridF, TPB, 0, stream>>>(x, y, xl, yl, out);
    }
}

// Round 11
// 35.152 us; speedup vs baseline: 1.1005x; 1.1005x over previous
//
#include <hip/hip_runtime.h>
#include <hip/hip_bf16.h>
#include <math.h>

// Problem constants (from reference): N=8 clouds, P=4096 points, D=3
constexpr int NB  = 8;
constexpr int PP  = 4096;

// Kernel A tiling
constexpr int TPB = 256;          // threads per block
constexpr int XPT = 8;            // x points per thread (VALU-bound: 14 cyc/wave-j vs ~9 LDS)
constexpr int XCH = TPB * XPT;    // 2048 x points per block
constexpr int NXC = PP / XCH;     // 2 x chunks
constexpr int NYC = 32;           // strided y slices (stride = NYC)
constexpr int YCH = PP / NYC;     // 128 y points per slice (FULL, inf-masked)
constexpr int GRIDA = 2 * NB * NXC * NYC;   // 1024 blocks, all uniform work

// Kernel B segmentation (byte-identical to R5)
constexpr int NSEG = 16;              // segments per (dir, cloud)
constexpr int SEGP = PP / NSEG;       // 256 x points per segment
constexpr int NPART = 2 * NB * NSEG;  // 256 partials

// ---------------------------------------------------------------------------
// Kernel A: per (dir, cloud, x-chunk, y-slice): partial min-d2 over the
// STRIDED y-slice {yc + 32*t} for 2048 x points. UNIFORM WORK: all blocks
// run the full 128 j's; invalid y points staged as (-0,-0,-0,+INF) so they
// drop out of the min (fma(px,0,INF)=INF, no NaN). Zero imbalance ->
// duration independent of lengths/dispatch. XPT=8 amortizes each broadcast
// ds_read_b128 over 28 VALU instrs -> VALU-bound (R7 probe: XPT=4 was
// ~25% LDS-bound at 9.26 cyc/wave-j). x-side whole-wave padding skip kept.
// ws layout identical to R5 (32 chunks per cloud).
// ---------------------------------------------------------------------------
__global__ __launch_bounds__(TPB, 4) void nn_partial(
    const float* __restrict__ x, const float* __restrict__ y,
    const int* __restrict__ xlen, const int* __restrict__ ylen,
    float* __restrict__ ws)
{
    __shared__ float4 sy[YCH];

    const int bid = (int)blockIdx.x;
    const int yc  = bid & (NYC - 1);
    const int xc  = (bid >> 5) & (NXC - 1);
    const int n   = (bid >> 6) & (NB - 1);
    const int dir = bid >> 9;

    const float* __restrict__ xs = dir ? y : x;    // query set
    const float* __restrict__ ys = dir ? x : y;    // search set
    const int yl = (dir ? xlen : ylen)[n];         // valid points in search set
    const int ql = (dir ? ylen : xlen)[n];         // valid points in query set

    // ---- stage strided y-slice as (-2y0,-2y1,-2y2,|y|^2); pad -> +INF ----
    const float* __restrict__ yb = ys + (size_t)n * PP * 3;
    if ((int)threadIdx.x < YCH) {
        const int p   = (int)threadIdx.x;
        const int idx = yc + NYC * p;              // < PP always
        float y0 = yb[idx * 3 + 0];
        float y1 = yb[idx * 3 + 1];
        float y2 = yb[idx * 3 + 2];
        if (idx < yl) {
            sy[p] = make_float4(-2.f * y0, -2.f * y1, -2.f * y2,
                                fmaf(y0, y0, fmaf(y1, y1, y2 * y2)));
        } else {
            sy[p] = make_float4(-0.f, -0.f, -0.f, INFINITY);
        }
    }

    // ---- load XPT x points, wave-contiguous: xi = wbase + k*64 + lane ----
    const int wave  = (int)threadIdx.x >> 6;
    const int lane  = (int)threadIdx.x & 63;
    const int wbase = xc * XCH + wave * (XPT * 64);   // 512 x points per wave

    float px0[XPT], px1[XPT], px2[XPT], a[XPT], emin[XPT];
    const float* __restrict__ xb = xs + (size_t)n * PP * 3;
#pragma unroll
    for (int k = 0; k < XPT; ++k) {
        const int xi = wbase + k * 64 + lane;
        px0[k] = xb[xi * 3 + 0];
        px1[k] = xb[xi * 3 + 1];
        px2[k] = xb[xi * 3 + 2];
        a[k]   = fmaf(px0[k], px0[k], fmaf(px1[k], px1[k], px2[k] * px2[k]));
        emin[k] = INFINITY;
    }
    __syncthreads();

    // whole-wave skip when every query row this wave owns is padding
    if (ql > wbase) {
#pragma unroll 2
        for (int j = 0; j < YCH; j += 2) {        // fixed 128-trip, uniform
            const float4 u = sy[j];
            const float4 v = sy[j + 1];
#pragma unroll
            for (int k = 0; k < XPT; ++k) {
                float e1 = fmaf(px0[k], u.x, fmaf(px1[k], u.y, fmaf(px2[k], u.z, u.w)));
                float e2 = fmaf(px0[k], v.x, fmaf(px1[k], v.y, fmaf(px2[k], v.z, v.w)));
                emin[k] = fminf(emin[k], fminf(e1, e2));   // -> v_min3_f32
            }
        }
    }

    float* __restrict__ w = ws + ((size_t)(dir * NB + n) * NYC + yc) * PP;
#pragma unroll
    for (int k = 0; k < XPT; ++k) {
        w[wbase + k * 64 + lane] = a[k] + emin[k];   // inf for skipped waves
    }
}

// ---------------------------------------------------------------------------
// Kernel B (byte-identical to R5): per (dir, cloud, segment): min over the
// 32 y-slices, mask padded x, sum, divide by max(len,1)*NB, write partial.
// 256 blocks, one element per thread, 32-deep MLP. Deterministic.
// ---------------------------------------------------------------------------
__global__ __launch_bounds__(256) void reduce_cloud(
    const float* __restrict__ ws,
    const int* __restrict__ xlen, const int* __restrict__ ylen,
    float* __restrict__ partial)
{
    const int b   = blockIdx.x;          // 0..255
    const int seg = b & (NSEG - 1);
    const int c   = b >> 4;              // 0..15
    const int dir = c >> 3;
    const int n   = c & (NB - 1);
    const int xl  = (dir ? ylen : xlen)[n];   // valid query points

    const float* __restrict__ w = ws + (size_t)c * NYC * PP;
    const int i = seg * SEGP + (int)threadIdx.x;

    float m = w[i];
#pragma unroll
    for (int ch = 1; ch < NYC; ++ch) m = fminf(m, w[(size_t)ch * PP + i]);
    float sum = (i < xl) ? m : 0.f;

    // block reduction (4 waves of 64)
#pragma unroll
    for (int off = 32; off > 0; off >>= 1) sum += __shfl_xor(sum, off);
    __shared__ float ls[4];
    const int lane = (int)threadIdx.x & 63;
    const int wv   = (int)threadIdx.x >> 6;
    if (lane == 0) ls[wv] = sum;
    __syncthreads();
    if (threadIdx.x == 0) {
        float tot = ls[0] + ls[1] + ls[2] + ls[3];
        int d = xl > 1 ? xl : 1;
        partial[b] = tot / (float)d / (float)NB;
    }
}

// ---------------------------------------------------------------------------
// Kernel C (identical to R5): sum the 256 partials -> scalar output.
// ---------------------------------------------------------------------------
__global__ __launch_bounds__(256) void final_sum(
    const float* __restrict__ partial, float* __restrict__ out)
{
    float v = partial[threadIdx.x];
#pragma unroll
    for (int off = 32; off > 0; off >>= 1) v += __shfl_xor(v, off);
    __shared__ float ls[4];
    const int lane = (int)threadIdx.x & 63;
    const int wv   = (int)threadIdx.x >> 6;
    if (lane == 0) ls[wv] = v;
    __syncthreads();
    if (threadIdx.x == 0) out[0] = ls[0] + ls[1] + ls[2] + ls[3];
}

// ---------------------------------------------------------------------------
// Fallback (ws too small): strided slices, multi-pass; block sum + atomicAdd
// of the pre-divided contribution. Needs d_out zeroed first.
// ---------------------------------------------------------------------------
__global__ __launch_bounds__(TPB) void chamfer_atomic(
    const float* __restrict__ x, const float* __restrict__ y,
    const int* __restrict__ xlen, const int* __restrict__ ylen,
    float* __restrict__ out)
{
    __shared__ float4 sy[YCH];

    int bid = blockIdx.x;
    const int xc  = bid & (NXC - 1);
    const int n   = (bid >> 1) & (NB - 1);
    const int dir = bid >> 4;

    const float* __restrict__ xs = dir ? y : x;
    const float* __restrict__ ys = dir ? x : y;
    const int yl = (dir ? xlen : ylen)[n];
    const int xl = (dir ? ylen : xlen)[n];

    float px0[XPT], px1[XPT], px2[XPT], a[XPT], emin[XPT];
    const int wave  = (int)threadIdx.x >> 6;
    const int lane  = (int)threadIdx.x & 63;
    const int wbase = xc * XCH + wave * (XPT * 64);
    const float* __restrict__ xb = xs + (size_t)n * PP * 3;
#pragma unroll
    for (int k = 0; k < XPT; ++k) {
        const int xi = wbase + k * 64 + lane;
        px0[k] = xb[xi * 3 + 0];
        px1[k] = xb[xi * 3 + 1];
        px2[k] = xb[xi * 3 + 2];
        a[k]   = fmaf(px0[k], px0[k], fmaf(px1[k], px1[k], px2[k] * px2[k]));
        emin[k] = INFINITY;
    }

    const float* __restrict__ yb = ys + (size_t)n * PP * 3;
    for (int yc = 0; yc < NYC; ++yc) {
        __syncthreads();
        if ((int)threadIdx.x < YCH) {
            const int p   = (int)threadIdx.x;
            const int idx = yc + NYC * p;
            float y0 = yb[idx * 3 + 0];
            float y1 = yb[idx * 3 + 1];
            float y2 = yb[idx * 3 + 2];
            if (idx < yl) {
                sy[p] = make_float4(-2.f * y0, -2.f * y1, -2.f * y2,
                                    fmaf(y0, y0, fmaf(y1, y1, y2 * y2)));
            } else {
                sy[p] = make_float4(-0.f, -0.f, -0.f, INFINITY);
            }
        }
        __syncthreads();
        for (int j = 0; j < YCH; ++j) {
            const float4 u = sy[j];
#pragma unroll
            for (int k = 0; k < XPT; ++k) {
                float e = fmaf(px0[k], u.x, fmaf(px1[k], u.y, fmaf(px2[k], u.z, u.w)));
                emin[k] = fminf(emin[k], e);
            }
        }
    }

    float sum = 0.f;
#pragma unroll
    for (int k = 0; k < XPT; ++k) {
        const int xi = wbase + k * 64 + lane;
        if (xi < xl) sum += a[k] + emin[k];
    }
#pragma unroll
    for (int off = 32; off > 0; off >>= 1) sum += __shfl_xor(sum, off);
    __shared__ float ls[4];
    if (lane == 0) ls[wave] = sum;
    __syncthreads();
    if (threadIdx.x == 0) {
        float tot = ls[0] + ls[1] + ls[2] + ls[3];
        int d = xl > 1 ? xl : 1;
        atomicAdd(out, tot / (float)d / (float)NB);
    }
}

extern "C" void kernel_launch(void* const* d_in, const int* in_sizes, int n_in,
                              void* d_out, int out_size, void* d_ws, size_t ws_size,
                              hipStream_t stream) {
    const float* x  = (const float*)d_in[0];
    const float* y  = (const float*)d_in[1];
    const int* xl   = (const int*)d_in[2];
    const int* yl   = (const int*)d_in[3];
    float* out      = (float*)d_out;

    const size_t ws_floats = (size_t)2 * NB * NYC * PP;             // partial d2 table
    const size_t ws_need   = (ws_floats + NPART) * sizeof(float);   // + partials

    if (ws_size >= ws_need) {
        float* ws      = (float*)d_ws;
        float* partial = ws + ws_floats;
        nn_partial<<<GRIDA, TPB, 0, stream>>>(x, y, xl, yl, ws);
        reduce_cloud<<<NPART, 256, 0, stream>>>(ws, xl, yl, partial);
        final_sum<<<1, 256, 0, stream>>>(partial, out);
    } else {
        hipMemsetAsync(d_out, 0, sizeof(float), stream);
        const int gridF = 2 * NB * NXC;         // 32 blocks
        chamfer_atomic<<<gridF, TPB, 0, stream>>>(x, y, xl, yl, out);
    }
}

// Round 12
// 29.154 us; speedup vs baseline: 1.3269x; 1.2057x over previous
//
#include <hip/hip_runtime.h>
#include <hip/hip_bf16.h>
#include <math.h>

// Problem constants (from reference): N=8 clouds, P=4096 points, D=3
constexpr int NB  = 8;
constexpr int PP  = 4096;

// Kernel A tiling (R5-proven layout: XPT=4, strided slices, 2048 blocks)
constexpr int TPB = 256;          // threads per block
constexpr int XPT = 4;            // x points per thread
constexpr int XCH = TPB * XPT;    // 1024 x points per block
constexpr int NXC = PP / XCH;     // 4 x chunks
constexpr int NYC = 32;           // strided y slices (stride = NYC)
constexpr int YCH = PP / NYC;     // 128 y points per slice
constexpr int GRIDA = 2 * NB * NXC * NYC;   // 2048 blocks

// Kernel B segmentation (byte-identical to R5)
constexpr int NSEG = 16;              // segments per (dir, cloud)
constexpr int SEGP = PP / NSEG;       // 256 x points per segment
constexpr int NPART = 2 * NB * NSEG;  // 256 partials

// ---------------------------------------------------------------------------
// Kernel A: R5's exact proven compute (15.8us via R7 probe) with two
// stall-coverage changes ONLY:
//   (1) j-loop unrolled by 4 -> 4 ds_read_b128 in flight per wave
//       (lgkmcnt waits amortized 2x vs unroll-2);
//   (2) __launch_bounds__(256,6) -> 6 blocks/CU resident (24 waves/CU,
//       6 waves/SIMD covering LDS latency instead of 4; VGPR cap ~84,
//       est. use ~60 -> no spill).
// Theory: R7/R11 data shows ~8 issue-slots/pair vs 3.75 ideal in both
// XPT configs -> ~50% slots idle on lgkm stalls, not VALU/LDS balance.
// ---------------------------------------------------------------------------
__global__ __launch_bounds__(TPB, 6) void nn_partial(
    const float* __restrict__ x, const float* __restrict__ y,
    const int* __restrict__ xlen, const int* __restrict__ ylen,
    float* __restrict__ ws)
{
    __shared__ float4 sy[YCH];

    const int bid = (int)blockIdx.x;
    const int yc  = bid & (NYC - 1);
    const int xc  = (bid >> 5) & (NXC - 1);
    const int n   = (bid >> 7) & (NB - 1);
    const int dir = bid >> 10;

    const float* __restrict__ xs = dir ? y : x;    // query set
    const float* __restrict__ ys = dir ? x : y;    // search set
    const int yl = (dir ? xlen : ylen)[n];         // valid points in search set
    const int ql = (dir ? ylen : xlen)[n];         // valid points in query set

    // ---- stage strided y-slice into LDS as (-2y0, -2y1, -2y2, |y|^2) ----
    const float* __restrict__ yb = ys + (size_t)n * PP * 3;
    if ((int)threadIdx.x < YCH) {
        const int p   = (int)threadIdx.x;
        const int idx = yc + NYC * p;              // < PP always
        float y0 = yb[idx * 3 + 0];
        float y1 = yb[idx * 3 + 1];
        float y2 = yb[idx * 3 + 2];
        sy[p] = make_float4(-2.f * y0, -2.f * y1, -2.f * y2,
                            fmaf(y0, y0, fmaf(y1, y1, y2 * y2)));
    }

    // ---- load XPT x points, wave-contiguous: xi = wbase + k*64 + lane ----
    const int wave  = (int)threadIdx.x >> 6;
    const int lane  = (int)threadIdx.x & 63;
    const int wbase = xc * XCH + wave * (XPT * 64);   // 256 x points per wave

    float px0[XPT], px1[XPT], px2[XPT], a[XPT], emin[XPT];
    const float* __restrict__ xb = xs + (size_t)n * PP * 3;
#pragma unroll
    for (int k = 0; k < XPT; ++k) {
        const int xi = wbase + k * 64 + lane;
        px0[k] = xb[xi * 3 + 0];
        px1[k] = xb[xi * 3 + 1];
        px2[k] = xb[xi * 3 + 2];
        a[k]   = fmaf(px0[k], px0[k], fmaf(px1[k], px1[k], px2[k] * px2[k]));
        emin[k] = INFINITY;
    }
    __syncthreads();

    // trip count: number of valid points in this strided slice
    int jend = (yl - yc + NYC - 1) >> 5;   // ceil((yl-yc)/32)
    if (jend > YCH) jend = YCH;

    // whole-wave skip when every query row this wave owns is padding
    if (ql > wbase && jend > 0) {
        int j = 0;
        const int j4 = jend & ~3;
#pragma unroll 1
        for (; j < j4; j += 4) {               // 4 ds_read_b128 in flight
            const float4 u0 = sy[j];
            const float4 u1 = sy[j + 1];
            const float4 u2 = sy[j + 2];
            const float4 u3 = sy[j + 3];
#pragma unroll
            for (int k = 0; k < XPT; ++k) {
                float e0 = fmaf(px0[k], u0.x, fmaf(px1[k], u0.y, fmaf(px2[k], u0.z, u0.w)));
                float e1 = fmaf(px0[k], u1.x, fmaf(px1[k], u1.y, fmaf(px2[k], u1.z, u1.w)));
                float e2 = fmaf(px0[k], u2.x, fmaf(px1[k], u2.y, fmaf(px2[k], u2.z, u2.w)));
                float e3 = fmaf(px0[k], u3.x, fmaf(px1[k], u3.y, fmaf(px2[k], u3.z, u3.w)));
                emin[k] = fminf(emin[k], fminf(fminf(e0, e1), fminf(e2, e3)));
            }
        }
        if (jend & 2) {
            const float4 u0 = sy[j];
            const float4 u1 = sy[j + 1];
#pragma unroll
            for (int k = 0; k < XPT; ++k) {
                float e0 = fmaf(px0[k], u0.x, fmaf(px1[k], u0.y, fmaf(px2[k], u0.z, u0.w)));
                float e1 = fmaf(px0[k], u1.x, fmaf(px1[k], u1.y, fmaf(px2[k], u1.z, u1.w)));
                emin[k] = fminf(emin[k], fminf(e0, e1));
            }
            j += 2;
        }
        if (jend & 1) {
            const float4 u0 = sy[j];
#pragma unroll
            for (int k = 0; k < XPT; ++k) {
                float e0 = fmaf(px0[k], u0.x, fmaf(px1[k], u0.y, fmaf(px2[k], u0.z, u0.w)));
                emin[k] = fminf(emin[k], e0);
            }
        }
    }

    float* __restrict__ w = ws + ((size_t)(dir * NB + n) * NYC + yc) * PP;
#pragma unroll
    for (int k = 0; k < XPT; ++k) {
        w[wbase + k * 64 + lane] = a[k] + emin[k];   // inf for skipped waves
    }
}

// ---------------------------------------------------------------------------
// Kernel B (byte-identical to R5): per (dir, cloud, segment): min over the
// 32 y-slices, mask padded x, sum, divide by max(len,1)*NB, write partial.
// ---------------------------------------------------------------------------
__global__ __launch_bounds__(256) void reduce_cloud(
    const float* __restrict__ ws,
    const int* __restrict__ xlen, const int* __restrict__ ylen,
    float* __restrict__ partial)
{
    const int b   = blockIdx.x;          // 0..255
    const int seg = b & (NSEG - 1);
    const int c   = b >> 4;              // 0..15
    const int dir = c >> 3;
    const int n   = c & (NB - 1);
    const int xl  = (dir ? ylen : xlen)[n];   // valid query points

    const float* __restrict__ w = ws + (size_t)c * NYC * PP;
    const int i = seg * SEGP + (int)threadIdx.x;

    float m = w[i];
#pragma unroll
    for (int ch = 1; ch < NYC; ++ch) m = fminf(m, w[(size_t)ch * PP + i]);
    float sum = (i < xl) ? m : 0.f;

    // block reduction (4 waves of 64)
#pragma unroll
    for (int off = 32; off > 0; off >>= 1) sum += __shfl_xor(sum, off);
    __shared__ float ls[4];
    const int lane = (int)threadIdx.x & 63;
    const int wv   = (int)threadIdx.x >> 6;
    if (lane == 0) ls[wv] = sum;
    __syncthreads();
    if (threadIdx.x == 0) {
        float tot = ls[0] + ls[1] + ls[2] + ls[3];
        int d = xl > 1 ? xl : 1;
        partial[b] = tot / (float)d / (float)NB;
    }
}

// ---------------------------------------------------------------------------
// Kernel C (identical to R5): sum the 256 partials -> scalar output.
// ---------------------------------------------------------------------------
__global__ __launch_bounds__(256) void final_sum(
    const float* __restrict__ partial, float* __restrict__ out)
{
    float v = partial[threadIdx.x];
#pragma unroll
    for (int off = 32; off > 0; off >>= 1) v += __shfl_xor(v, off);
    __shared__ float ls[4];
    const int lane = (int)threadIdx.x & 63;
    const int wv   = (int)threadIdx.x >> 6;
    if (lane == 0) ls[wv] = v;
    __syncthreads();
    if (threadIdx.x == 0) out[0] = ls[0] + ls[1] + ls[2] + ls[3];
}

// ---------------------------------------------------------------------------
// Fallback (ws too small): strided slices, multi-pass; block sum + atomicAdd
// of the pre-divided contribution. Needs d_out zeroed first.
// ---------------------------------------------------------------------------
__global__ __launch_bounds__(TPB) void chamfer_atomic(
    const float* __restrict__ x, const float* __restrict__ y,
    const int* __restrict__ xlen, const int* __restrict__ ylen,
    float* __restrict__ out)
{
    __shared__ float4 sy[YCH];

    int bid = blockIdx.x;
    const int xc  = bid & (NXC - 1);
    const int n   = (bid >> 2) & (NB - 1);
    const int dir = bid >> 5;

    const float* __restrict__ xs = dir ? y : x;
    const float* __restrict__ ys = dir ? x : y;
    const int yl = (dir ? xlen : ylen)[n];
    const int xl = (dir ? ylen : xlen)[n];

    float px0[XPT], px1[XPT], px2[XPT], a[XPT], emin[XPT];
    const int wave  = (int)threadIdx.x >> 6;
    const int lane  = (int)threadIdx.x & 63;
    const int wbase = xc * XCH + wave * (XPT * 64);
    const float* __restrict__ xb = xs + (size_t)n * PP * 3;
#pragma unroll
    for (int k = 0; k < XPT; ++k) {
        const int xi = wbase + k * 64 + lane;
        px0[k] = xb[xi * 3 + 0];
        px1[k] = xb[xi * 3 + 1];
        px2[k] = xb[xi * 3 + 2];
        a[k]   = fmaf(px0[k], px0[k], fmaf(px1[k], px1[k], px2[k] * px2[k]));
        emin[k] = INFINITY;
    }

    const float* __restrict__ yb = ys + (size_t)n * PP * 3;
    for (int yc = 0; yc < NYC; ++yc) {
        __syncthreads();
        if ((int)threadIdx.x < YCH) {
            const int p   = (int)threadIdx.x;
            const int idx = yc + NYC * p;
            float y0 = yb[idx * 3 + 0];
            float y1 = yb[idx * 3 + 1];
            float y2 = yb[idx * 3 + 2];
            sy[p] = make_float4(-2.f * y0, -2.f * y1, -2.f * y2,
                                fmaf(y0, y0, fmaf(y1, y1, y2 * y2)));
        }
        __syncthreads();
        int jend = (yl - yc + NYC - 1) >> 5;
        if (jend > YCH) jend = YCH;
        for (int j = 0; j < jend; ++j) {
            const float4 u = sy[j];
#pragma unroll
            for (int k = 0; k < XPT; ++k) {
                float e = fmaf(px0[k], u.x, fmaf(px1[k], u.y, fmaf(px2[k], u.z, u.w)));
                emin[k] = fminf(emin[k], e);
            }
        }
    }

    float sum = 0.f;
#pragma unroll
    for (int k = 0; k < XPT; ++k) {
        const int xi = wbase + k * 64 + lane;
        if (xi < xl) sum += a[k] + emin[k];
    }
#pragma unroll
    for (int off = 32; off > 0; off >>= 1) sum += __shfl_xor(sum, off);
    __shared__ float ls[4];
    if (lane == 0) ls[wave] = sum;
    __syncthreads();
    if (threadIdx.x == 0) {
        float tot = ls[0] + ls[1] + ls[2] + ls[3];
        int d = xl > 1 ? xl : 1;
        atomicAdd(out, tot / (float)d / (float)NB);
    }
}

extern "C" void kernel_launch(void* const* d_in, const int* in_sizes, int n_in,
                              void* d_out, int out_size, void* d_ws, size_t ws_size,
                              hipStream_t stream) {
    const float* x  = (const float*)d_in[0];
    const float* y  = (const float*)d_in[1];
    const int* xl   = (const int*)d_in[2];
    const int* yl   = (const int*)d_in[3];
    float* out      = (float*)d_out;

    const size_t ws_floats = (size_t)2 * NB * NYC * PP;             // partial d2 table
    const size_t ws_need   = (ws_floats + NPART) * sizeof(float);   // + partials

    if (ws_size >= ws_need) {
        float* ws      = (float*)d_ws;
        float* partial = ws + ws_floats;
        nn_partial<<<GRIDA, TPB, 0, stream>>>(x, y, xl, yl, ws);
        reduce_cloud<<<NPART, 256, 0, stream>>>(ws, xl, yl, partial);
        final_sum<<<1, 256, 0, stream>>>(partial, out);
    } else {
        hipMemsetAsync(d_out, 0, sizeof(float), stream);
        const int gridF = 2 * NB * NXC;         // 64 blocks
        chamfer_atomic<<<gridF, TPB, 0, stream>>>(x, y, xl, yl, out);
    }
}